// Round 5
// baseline (529.245 us; speedup 1.0000x reference)
//
#include <hip/hip_runtime.h>
#include <hip/hip_bf16.h>

#define D_DIM 512
#define NSEQ  4096
#define BATCH 4
#define SCALE 0.125f

typedef __attribute__((ext_vector_type(8)))  short short8;
typedef __attribute__((ext_vector_type(16))) float floatx16;

__device__ __forceinline__ unsigned short f2bf(float f) {
    __hip_bfloat16 h = __float2bfloat16(f);
    return *reinterpret_cast<unsigned short*>(&h);
}

__device__ __forceinline__ floatx16 mfma_bf16(short8 a, short8 b, floatx16 c) {
    return __builtin_amdgcn_mfma_f32_32x32x16_bf16(a, b, c, 0, 0, 0);
}

// ============================================================
// Kernel 1: QKV projection, bf16 MFMA, coalesced LDS-transpose epilogue.
// Outputs: qs=(q+b)*SCALE [tok][d], kk=k+b [tok][d], vT=(v+b) [b][d][tok]
// ============================================================
#define K1_BK 64
#define K1_STRIDE 72     // staging row stride (elems)
#define C_STR 136        // epilogue row stride (elems); 272 B, 16B-aligned

__global__ __launch_bounds__(256, 4) void qkv_gemm(
    const float* __restrict__ x, const float* __restrict__ W,
    const float* __restrict__ bias,
    unsigned short* __restrict__ qs, unsigned short* __restrict__ kk,
    unsigned short* __restrict__ vT)
{
    __shared__ __align__(16) unsigned short sm1[2 * 128 * K1_STRIDE]; // 36864 B
    unsigned short* Xs = sm1;
    unsigned short* Ws = sm1 + 128 * K1_STRIDE;

    const int t = threadIdx.x;
    const int lane = t & 63, w = t >> 6;
    const int l31 = lane & 31, lh = lane >> 5;
    const int wm = w >> 1, we = w & 1;
    const int m0 = blockIdx.x * 128;
    const int n0 = blockIdx.y * 128;

    floatx16 a00, a01, a10, a11;
#pragma unroll
    for (int r = 0; r < 16; r++) { a00[r] = 0.f; a01[r] = 0.f; a10[r] = 0.f; a11[r] = 0.f; }

    for (int kc = 0; kc < D_DIM / K1_BK; kc++) {
        const int k0 = kc * K1_BK;
        __syncthreads();
#pragma unroll
        for (int p = 0; p < 8; p++) {
            int id = t + p * 256;
            int row = id >> 4, kq = id & 15;
            float4 xv = *(const float4*)(x + (size_t)(m0 + row) * D_DIM + k0 + 4 * kq);
            ushort4 hx; hx.x = f2bf(xv.x); hx.y = f2bf(xv.y); hx.z = f2bf(xv.z); hx.w = f2bf(xv.w);
            *(ushort4*)&Xs[row * K1_STRIDE + 4 * kq] = hx;
            float4 wv = *(const float4*)(W + (size_t)(n0 + row) * D_DIM + k0 + 4 * kq);
            ushort4 hw; hw.x = f2bf(wv.x); hw.y = f2bf(wv.y); hw.z = f2bf(wv.z); hw.w = f2bf(wv.w);
            *(ushort4*)&Ws[row * K1_STRIDE + 4 * kq] = hw;
        }
        __syncthreads();
#pragma unroll
        for (int ks = 0; ks < 4; ks++) {
            const int co = ks * 16 + lh * 8;
            short8 fa0 = *(const short8*)&Xs[(wm * 64 + l31) * K1_STRIDE + co];
            short8 fa1 = *(const short8*)&Xs[(wm * 64 + 32 + l31) * K1_STRIDE + co];
            short8 fb0 = *(const short8*)&Ws[(we * 64 + l31) * K1_STRIDE + co];
            short8 fb1 = *(const short8*)&Ws[(we * 64 + 32 + l31) * K1_STRIDE + co];
            a00 = mfma_bf16(fa0, fb0, a00);
            a01 = mfma_bf16(fa0, fb1, a01);
            a10 = mfma_bf16(fa1, fb0, a10);
            a11 = mfma_bf16(fa1, fb1, a11);
        }
    }

    // ---- epilogue: C -> LDS (bias+scale+bf16), then coalesced stores ----
    const int seg = n0 >> 9;   // 0:Q 1:K 2:V (uniform per block; 128 | 512)
    __syncthreads();           // all staging reads done; reuse sm1 as C[128][C_STR]
    unsigned short* C = sm1;
#pragma unroll
    for (int jt = 0; jt < 2; jt++) {
        const int e_loc = we * 64 + jt * 32 + l31;
        const float bv = bias[n0 + e_loc];
#pragma unroll
        for (int it = 0; it < 2; it++) {
            const int mb = wm * 64 + it * 32;
            const floatx16& av = (it == 0) ? ((jt == 0) ? a00 : a01)
                                           : ((jt == 0) ? a10 : a11);
#pragma unroll
            for (int r = 0; r < 16; r++) {
                int m_loc = mb + (r & 3) + 8 * (r >> 2) + 4 * lh;
                float v = av[r] + bv;
                C[m_loc * C_STR + e_loc] = f2bf(seg == 0 ? v * SCALE : v);
            }
        }
    }
    __syncthreads();

    if (seg < 2) {
        unsigned short* dst = (seg == 0) ? qs : kk;
        const int ecol0 = n0 & 511;
#pragma unroll
        for (int p = 0; p < 8; p++) {
            int id = t + p * 256;
            int m = id >> 4, c8 = id & 15;
            uint4 v = *(const uint4*)&C[m * C_STR + c8 * 8];
            *(uint4*)(dst + (size_t)(m0 + m) * D_DIM + ecol0 + c8 * 8) = v;
        }
    } else {
        const int bb = m0 >> 12, tok0 = m0 & 4095, d0 = n0 - 1024;
#pragma unroll
        for (int p = 0; p < 8; p++) {
            int id = t + p * 256;
            int dr = id >> 4, mc = id & 15;
            unsigned short h[8];
#pragma unroll
            for (int xq = 0; xq < 8; xq++) h[xq] = C[(mc * 8 + xq) * C_STR + dr];
            *(uint4*)(vT + ((size_t)(bb * 512 + d0 + dr)) * 4096 + tok0 + mc * 8) =
                *(uint4*)h;
        }
    }
}

// ============================================================
// Kernel 2: flash attention. BQ=64, BK=256, 512 thr / 8 waves.
// Fragment-tiled conflict-free LDS layouts; Q staged once (ks<30 in LDS,
// ks 30/31 per-lane regs); K/V double-buffered (shared 66 KB region);
// S^T = K.Q^T so softmax stats live on lane&31.
// ============================================================
#define FA_BK 256
#define KPL 4128     // K plane stride (elems): 256*16 + 32 pad (bank offset)
#define VPL 8200     // V plane stride (elems): 512*16 + 8 pad
#define BUFSTRIDE 16512  // elems: one K buf (4*KPL); V bufs use same stride

__global__ __launch_bounds__(512, 2) void flash_attn(
    const unsigned short* __restrict__ qs, const unsigned short* __restrict__ kk,
    const unsigned short* __restrict__ vT, float* __restrict__ out)
{
    __shared__ __align__(16) unsigned char smem[162816];
    unsigned short* KB = (unsigned short*)smem;              // 2 bufs @ 0 / 33024 B
    unsigned short* VB = (unsigned short*)smem;              // 2 bufs, same stride
    unsigned short* Qs = (unsigned short*)(smem + 66048);    // [30][64][16] = 61440 B
    unsigned short* P  = (unsigned short*)(smem + 127488);   // [16][64][16] = 32768 B
    float* pmax    = (float*)(smem + 160256);                // [64][4]
    float* psum    = (float*)(smem + 161280);                // [64][4]
    float* alpha_s = (float*)(smem + 162304);                // [64]
    float* l_s     = (float*)(smem + 162560);                // [64]

    const int t = threadIdx.x;
    const int lane = t & 63, w = t >> 6;
    const int l31 = lane & 31, lh = lane >> 5;
    const int wi = w & 1, wjj = w >> 1;
    const int b  = blockIdx.y;
    const int q0 = blockIdx.x * 64;
    const size_t qbase = ((size_t)b * NSEQ + q0) * D_DIM;
    const size_t kbase = (size_t)b * NSEQ * D_DIM;
    const size_t vbase = (size_t)b * D_DIM * NSEQ;

    const int i_my = wi * 32 + l31;

    // ---- stage Q once, fragment-tiled (permutation => conflict-free) ----
#pragma unroll
    for (int p = 0; p < 8; p++) {
        int id = t + p * 512;
        int ks = id >> 7;
        if (ks < 30) {
            int r = id & 127, i = r >> 1, lo = r & 1;
            uint4 v = *(const uint4*)(qs + qbase + (size_t)i * D_DIM + ks * 16 + lo * 8);
            *(uint4*)&Qs[(ks * 64 + i) * 16 + lo * 8] = v;
        }
    }
    // per-lane Q register fragments for ks 30, 31 (once per kernel)
    short8 qr30 = *(const short8*)(qs + qbase + (size_t)(wi * 32 + l31) * D_DIM + 480 + lh * 8);
    short8 qr31 = *(const short8*)(qs + qbase + (size_t)(wi * 32 + l31) * D_DIM + 496 + lh * 8);

    floatx16 o00, o01, o10, o11;
#pragma unroll
    for (int r = 0; r < 16; r++) { o00[r] = 0.f; o01[r] = 0.f; o10[r] = 0.f; o11[r] = 0.f; }
    float m_st = -__builtin_inff(), l_st = 0.f;

    for (int kt = 0; kt < NSEQ; kt += FA_BK) {
        // ================= S^T = K.Q^T, K double-buffered dc=64 ===========
        floatx16 s0, s1;
#pragma unroll
        for (int r = 0; r < 16; r++) { s0[r] = 0.f; s1[r] = 0.f; }

        uint4 kv[4];
#pragma unroll
        for (int p = 0; p < 4; p++) {
            int id = t + p * 512, j = id >> 3, c8 = id & 7;
            kv[p] = *(const uint4*)(kk + kbase + (size_t)(kt + j) * D_DIM + c8 * 8);
        }
#pragma unroll
        for (int p = 0; p < 4; p++) {
            int id = t + p * 512, j = id >> 3, c8 = id & 7;
            *(uint4*)&KB[(c8 >> 1) * KPL + j * 16 + (c8 & 1) * 8] = kv[p];
        }

#pragma unroll
        for (int c = 0; c < 8; c++) {
            __syncthreads();
            if (c < 7) {
#pragma unroll
                for (int p = 0; p < 4; p++) {
                    int id = t + p * 512, j = id >> 3, c8 = id & 7;
                    kv[p] = *(const uint4*)(kk + kbase + (size_t)(kt + j) * D_DIM
                                            + (c + 1) * 64 + c8 * 8);
                }
            }
            const unsigned short* kb = KB + (c & 1) * BUFSTRIDE;
            const unsigned short* ka0 = kb + (wjj * 64 + l31) * 16 + lh * 8;
            const unsigned short* ka1 = kb + (wjj * 64 + 32 + l31) * 16 + lh * 8;
#pragma unroll
            for (int ksl = 0; ksl < 4; ksl++) {
                const int ksg = c * 4 + ksl;
                short8 fb;
                if (ksg < 30)      fb = *(const short8*)&Qs[(ksg * 64 + i_my) * 16 + lh * 8];
                else if (ksg == 30) fb = qr30;
                else                fb = qr31;
                short8 fa0 = *(const short8*)(ka0 + ksl * KPL);
                short8 fa1 = *(const short8*)(ka1 + ksl * KPL);
                s0 = mfma_bf16(fa0, fb, s0);
                s1 = mfma_bf16(fa1, fb, s1);
            }
            if (c < 7) {
#pragma unroll
                for (int p = 0; p < 4; p++) {
                    int id = t + p * 512, j = id >> 3, c8 = id & 7;
                    *(uint4*)&KB[((c + 1) & 1) * BUFSTRIDE + (c8 >> 1) * KPL + j * 16
                                 + (c8 & 1) * 8] = kv[p];
                }
            }
        }

        // ================= online softmax =================================
        float mx = -__builtin_inff();
#pragma unroll
        for (int r = 0; r < 16; r++) mx = fmaxf(mx, fmaxf(s0[r], s1[r]));
        mx = fmaxf(mx, __shfl_xor(mx, 32));
        if (lh == 0) pmax[i_my * 4 + wjj] = mx;
        __syncthreads();                                     // sync1

        float4 pm = *(float4*)&pmax[i_my * 4];
        const float m_new = fmaxf(m_st, fmaxf(fmaxf(pm.x, pm.y), fmaxf(pm.z, pm.w)));
        const float alpha = __expf(m_st - m_new);
        m_st = m_new;

        // issue V stage-0 loads early (consumed after sync2)
        uint4 vv[4];
#pragma unroll
        for (int p = 0; p < 4; p++) {
            int id = t + p * 512, d = id >> 2, jj = id & 3;
            vv[p] = *(const uint4*)(vT + vbase + (size_t)d * NSEQ + kt + jj * 8);
        }

        float sum = 0.f;
        {
            const int jb0 = wjj * 64, jb1 = wjj * 64 + 32;
#pragma unroll
            for (int q = 0; q < 4; q++) {
                const int jq = 8 * q + 4 * lh;
                float p0 = __expf(s0[4*q+0] - m_new), p1 = __expf(s0[4*q+1] - m_new);
                float p2 = __expf(s0[4*q+2] - m_new), p3 = __expf(s0[4*q+3] - m_new);
                sum += (p0 + p1) + (p2 + p3);
                ushort4 h; h.x = f2bf(p0); h.y = f2bf(p1); h.z = f2bf(p2); h.w = f2bf(p3);
                *(ushort4*)&P[((jb0 + jq) >> 4) * 1024 + i_my * 16 + ((jb0 + jq) & 15)] = h;
            }
#pragma unroll
            for (int q = 0; q < 4; q++) {
                const int jq = 8 * q + 4 * lh;
                float p0 = __expf(s1[4*q+0] - m_new), p1 = __expf(s1[4*q+1] - m_new);
                float p2 = __expf(s1[4*q+2] - m_new), p3 = __expf(s1[4*q+3] - m_new);
                sum += (p0 + p1) + (p2 + p3);
                ushort4 h; h.x = f2bf(p0); h.y = f2bf(p1); h.z = f2bf(p2); h.w = f2bf(p3);
                *(ushort4*)&P[((jb1 + jq) >> 4) * 1024 + i_my * 16 + ((jb1 + jq) & 15)] = h;
            }
        }
        sum += __shfl_xor(sum, 32);
        if (lh == 0) psum[i_my * 4 + wjj] = sum;
        if (lh == 0 && wjj == 0) alpha_s[i_my] = alpha;
        __syncthreads();                                     // sync2

        float4 ps = *(float4*)&psum[i_my * 4];
        l_st = l_st * alpha + ((ps.x + ps.y) + (ps.z + ps.w));

        float av[2][16];
        bool ch = false;
#pragma unroll
        for (int it = 0; it < 2; it++)
#pragma unroll
            for (int q = 0; q < 4; q++) {
                float4 a4 = *(float4*)&alpha_s[it * 32 + 8 * q + 4 * lh];
                av[it][4*q+0] = a4.x; av[it][4*q+1] = a4.y;
                av[it][4*q+2] = a4.z; av[it][4*q+3] = a4.w;
                ch = ch || (a4.x != 1.f) || (a4.y != 1.f) || (a4.z != 1.f) || (a4.w != 1.f);
            }
        if (__any(ch)) {
#pragma unroll
            for (int r = 0; r < 16; r++) {
                o00[r] *= av[0][r]; o01[r] *= av[0][r];
                o10[r] *= av[1][r]; o11[r] *= av[1][r];
            }
        }

        // write V stage 0 (safe: all waves past K-buf0 reads since sync1/2)
#pragma unroll
        for (int p = 0; p < 4; p++) {
            int id = t + p * 512, d = id >> 2, jj = id & 3;
            *(uint4*)&VB[(jj >> 1) * VPL + d * 16 + (jj & 1) * 8] = vv[p];
        }

        // ================= O += P.V, V double-buffered (32 j/stage) =======
#pragma unroll
        for (int s = 0; s < 8; s++) {
            __syncthreads();
            if (s < 7) {
#pragma unroll
                for (int p = 0; p < 4; p++) {
                    int id = t + p * 512, d = id >> 2, jj = id & 3;
                    vv[p] = *(const uint4*)(vT + vbase + (size_t)d * NSEQ + kt
                                            + (s + 1) * 32 + jj * 8);
                }
            }
            const unsigned short* vb = VB + (s & 1) * BUFSTRIDE;
            const unsigned short* v0 = vb + (w * 64 + l31) * 16 + lh * 8;
            const unsigned short* v1 = vb + (w * 64 + 32 + l31) * 16 + lh * 8;
#pragma unroll
            for (int ksj = 0; ksj < 2; ksj++) {
                const int kp = 2 * s + ksj;
                short8 pa0 = *(const short8*)&P[(kp * 64 + l31) * 16 + lh * 8];
                short8 pa1 = *(const short8*)&P[(kp * 64 + 32 + l31) * 16 + lh * 8];
                short8 vb0 = *(const short8*)(v0 + ksj * VPL);
                short8 vb1 = *(const short8*)(v1 + ksj * VPL);
                o00 = mfma_bf16(pa0, vb0, o00);
                o01 = mfma_bf16(pa0, vb1, o01);
                o10 = mfma_bf16(pa1, vb0, o10);
                o11 = mfma_bf16(pa1, vb1, o11);
            }
            if (s < 7) {
#pragma unroll
                for (int p = 0; p < 4; p++) {
                    int id = t + p * 512, d = id >> 2, jj = id & 3;
                    *(uint4*)&VB[((s + 1) & 1) * BUFSTRIDE + (jj >> 1) * VPL + d * 16
                                 + (jj & 1) * 8] = vv[p];
                }
            }
        }
    }

    // ================= epilogue: O / l ===================================
    if (lh == 0 && wjj == 0) l_s[i_my] = l_st;
    __syncthreads();
    float iv[2][16];
#pragma unroll
    for (int it = 0; it < 2; it++)
#pragma unroll
        for (int q = 0; q < 4; q++) {
            float4 l4 = *(float4*)&l_s[it * 32 + 8 * q + 4 * lh];
            iv[it][4*q+0] = 1.f / l4.x; iv[it][4*q+1] = 1.f / l4.y;
            iv[it][4*q+2] = 1.f / l4.z; iv[it][4*q+3] = 1.f / l4.w;
        }
#pragma unroll
    for (int it = 0; it < 2; it++) {
        const floatx16& oa = (it == 0) ? o00 : o10;
        const floatx16& ob = (it == 0) ? o01 : o11;
#pragma unroll
        for (int r = 0; r < 16; r++) {
            const int i = it * 32 + (r & 3) + 8 * (r >> 2) + 4 * lh;
            const size_t rowb = ((size_t)b * NSEQ + q0 + i) * D_DIM;
            out[rowb + w * 64 + l31]      = oa[r] * iv[it][r];
            out[rowb + w * 64 + 32 + l31] = ob[r] * iv[it][r];
        }
    }
}

extern "C" void kernel_launch(void* const* d_in, const int* in_sizes, int n_in,
                              void* d_out, int out_size, void* d_ws, size_t ws_size,
                              hipStream_t stream)
{
    (void)in_sizes; (void)n_in; (void)out_size; (void)ws_size;
    const float* x    = (const float*)d_in[0];
    const float* W    = (const float*)d_in[1];
    const float* bias = (const float*)d_in[2];
    float* out = (float*)d_out;

    unsigned short* qs = (unsigned short*)d_ws;              // [16384][512]
    unsigned short* kk = qs + (size_t)16384 * 512;           // [16384][512]
    unsigned short* vT = kk + (size_t)16384 * 512;           // [4][512][4096]

    qkv_gemm<<<dim3(128, 12), 256, 0, stream>>>(x, W, bias, qs, kk, vT);
    flash_attn<<<dim3(NSEQ / 64, BATCH), 512, 0, stream>>>(qs, kk, vT, out);
}

// Round 6
// 413.446 us; speedup vs baseline: 1.2801x; 1.2801x over previous
//
#include <hip/hip_runtime.h>
#include <hip/hip_bf16.h>

#define D_DIM 512
#define NSEQ  4096
#define BATCH 4
#define SCALE 0.125f

typedef __attribute__((ext_vector_type(8)))  short short8;
typedef __attribute__((ext_vector_type(16))) float floatx16;

__device__ __forceinline__ unsigned short f2bf(float f) {
    __hip_bfloat16 h = __float2bfloat16(f);
    return *reinterpret_cast<unsigned short*>(&h);
}

__device__ __forceinline__ floatx16 mfma_bf16(short8 a, short8 b, floatx16 c) {
    return __builtin_amdgcn_mfma_f32_32x32x16_bf16(a, b, c, 0, 0, 0);
}

// ============================================================
// Kernel 1: QKV projection, bf16 MFMA. BK=64, 3 blocks/CU.
// Outputs: qs=(q+b)*SCALE [tok][d], kk=k+b [tok][d], vT=(v+b) [b][d][tok]
// ============================================================
#define K1_BK 64
#define K1_STRIDE 72   // elems; 144B rows; word-stride 36 ≡ 4 mod 32 (conflict-free class)

__global__ __launch_bounds__(256, 3) void qkv_gemm(
    const float* __restrict__ x, const float* __restrict__ W,
    const float* __restrict__ bias,
    unsigned short* __restrict__ qs, unsigned short* __restrict__ kk,
    unsigned short* __restrict__ vT)
{
    __shared__ __align__(16) unsigned short Xs[128 * K1_STRIDE];
    __shared__ __align__(16) unsigned short Ws[128 * K1_STRIDE];

    const int t = threadIdx.x;
    const int lane = t & 63, w = t >> 6;
    const int l31 = lane & 31, lh = lane >> 5;
    const int wm = w >> 1, we = w & 1;
    const int m0 = blockIdx.x * 128;
    const int n0 = blockIdx.y * 128;

    floatx16 a00, a01, a10, a11;
#pragma unroll
    for (int r = 0; r < 16; r++) { a00[r] = 0.f; a01[r] = 0.f; a10[r] = 0.f; a11[r] = 0.f; }

    for (int kc = 0; kc < D_DIM / K1_BK; kc++) {
        const int k0 = kc * K1_BK;
        __syncthreads();
#pragma unroll
        for (int p = 0; p < 8; p++) {
            int id = t + p * 256;
            int row = id >> 4, kq = id & 15;
            float4 xv = *(const float4*)(x + (size_t)(m0 + row) * D_DIM + k0 + 4 * kq);
            ushort4 hx; hx.x = f2bf(xv.x); hx.y = f2bf(xv.y); hx.z = f2bf(xv.z); hx.w = f2bf(xv.w);
            *(ushort4*)&Xs[row * K1_STRIDE + 4 * kq] = hx;
            float4 wv = *(const float4*)(W + (size_t)(n0 + row) * D_DIM + k0 + 4 * kq);
            ushort4 hw; hw.x = f2bf(wv.x); hw.y = f2bf(wv.y); hw.z = f2bf(wv.z); hw.w = f2bf(wv.w);
            *(ushort4*)&Ws[row * K1_STRIDE + 4 * kq] = hw;
        }
        __syncthreads();
#pragma unroll
        for (int ks = 0; ks < 4; ks++) {
            const int co = ks * 16 + lh * 8;
            short8 fa0 = *(const short8*)&Xs[(wm * 64 + l31) * K1_STRIDE + co];
            short8 fa1 = *(const short8*)&Xs[(wm * 64 + 32 + l31) * K1_STRIDE + co];
            short8 fb0 = *(const short8*)&Ws[(we * 64 + l31) * K1_STRIDE + co];
            short8 fb1 = *(const short8*)&Ws[(we * 64 + 32 + l31) * K1_STRIDE + co];
            a00 = mfma_bf16(fa0, fb0, a00);
            a01 = mfma_bf16(fa0, fb1, a01);
            a10 = mfma_bf16(fa1, fb0, a10);
            a11 = mfma_bf16(fa1, fb1, a11);
        }
    }

    // epilogue (R3-proven): C/D layout col=lane&31, row=(r&3)+8*(r>>2)+4*lh
    const size_t seg_sz = (size_t)BATCH * NSEQ * D_DIM;
#pragma unroll
    for (int jt = 0; jt < 2; jt++) {
        const int e = n0 + we * 64 + jt * 32 + l31;
        const float bv = bias[e];
#pragma unroll
        for (int it = 0; it < 2; it++) {
            const int mb = m0 + wm * 64 + it * 32;
            const floatx16& av = (it == 0) ? ((jt == 0) ? a00 : a01)
                                           : ((jt == 0) ? a10 : a11);
            if (e < 512) {
#pragma unroll
                for (int r = 0; r < 16; r++) {
                    int m = mb + (r & 3) + 8 * (r >> 2) + 4 * lh;
                    qs[(size_t)m * D_DIM + e] = f2bf((av[r] + bv) * SCALE);
                }
            } else if (e < 1024) {
#pragma unroll
                for (int r = 0; r < 16; r++) {
                    int m = mb + (r & 3) + 8 * (r >> 2) + 4 * lh;
                    kk[(size_t)m * D_DIM + (e - 512)] = f2bf(av[r] + bv);
                }
            } else {
                const int d = e - 1024;
#pragma unroll
                for (int q = 0; q < 4; q++) {
                    int mq = mb + 8 * q + 4 * lh;
                    int bb = mq >> 12; int tok = mq & 4095;
                    ushort4 hv;
                    hv.x = f2bf(av[4 * q + 0] + bv); hv.y = f2bf(av[4 * q + 1] + bv);
                    hv.z = f2bf(av[4 * q + 2] + bv); hv.w = f2bf(av[4 * q + 3] + bv);
                    *(ushort4*)&vT[((size_t)bb * 512 + d) * 4096 + tok] = hv;
                }
            }
        }
    }
    (void)seg_sz;
}

// ============================================================
// Kernel 2: flash attention, 1024 threads / 16 waves, BQ=64, BK=256.
// QK: waves = 2 i-tiles x 8 j-tiles (one 32x32 S^T tile per wave).
// PV: waves = 2 i-tiles x 8 d-chunks (two 32x32 O tiles per wave).
// R3 stride classes (word-stride ≡ 4 mod 32) throughout. 18 barriers/kt.
// ============================================================
#define QK_STR 136   // Qc/Kc row stride (elems)
#define P_STR  264   // P row stride
#define V_STR  72    // Vs row stride

__global__ __launch_bounds__(1024) void flash_attn(
    const unsigned short* __restrict__ qs, const unsigned short* __restrict__ kk,
    const unsigned short* __restrict__ vT, float* __restrict__ out)
{
    __shared__ __align__(16) unsigned char smem[125440];
    unsigned short* Kc = (unsigned short*)smem;              // [256][136] = 69632 B
    unsigned short* Qc = (unsigned short*)(smem + 69632);    // [64][136]  = 17408 B
    unsigned short* Vs = (unsigned short*)smem;              // [512][72]  = 73728 B (union)
    unsigned short* P  = (unsigned short*)(smem + 87040);    // [64][264]  = 33792 B
    float* pmax    = (float*)(smem + 120832);                // [64][8]
    float* psum    = (float*)(smem + 122880);                // [64][8]
    float* alpha_s = (float*)(smem + 124928);                // [64]
    float* l_s     = (float*)(smem + 125184);                // [64]

    const int t = threadIdx.x;
    const int lane = t & 63, w = t >> 6;                     // w: 0..15
    const int l31 = lane & 31, lh = lane >> 5;
    const int wi = w & 1;                                    // i-tile (QK & PV)
    const int wjj = w >> 1;                                  // j-tile (QK) / d-chunk (PV)
    const int b  = blockIdx.y;
    const int q0 = blockIdx.x * 64;
    const size_t qbase = ((size_t)b * NSEQ + q0) * D_DIM;
    const size_t kbase = (size_t)b * NSEQ * D_DIM;
    const size_t vbase = (size_t)b * D_DIM * NSEQ;

    const int i_my = wi * 32 + l31;

    floatx16 oA, oB;                                         // O[i-tile][d: wjj*64 +0/+32]
#pragma unroll
    for (int r = 0; r < 16; r++) { oA[r] = 0.f; oB[r] = 0.f; }
    float m_st = -__builtin_inff(), l_st = 0.f;

    for (int kt = 0; kt < NSEQ; kt += 256) {
        // ================= S^T = K.Q^T (dc-chunked 128) ===================
        floatx16 s;
#pragma unroll
        for (int r = 0; r < 16; r++) s[r] = 0.f;

        for (int dcs = 0; dcs < 4; dcs++) {
            const int dc = dcs * 128;
            __syncthreads();
            {   // Qc: 64 x 128, 1 uint4/thread
                int row = t >> 4, c8 = t & 15;
                uint4 v = *(const uint4*)(qs + qbase + (size_t)row * D_DIM + dc + c8 * 8);
                *(uint4*)&Qc[row * QK_STR + c8 * 8] = v;
            }
#pragma unroll
            for (int p = 0; p < 4; p++) {                    // Kc: 256 x 128, 4/thread
                int id = t + p * 1024;
                int row = id >> 4, c8 = id & 15;
                uint4 v = *(const uint4*)(kk + kbase + (size_t)(kt + row) * D_DIM + dc + c8 * 8);
                *(uint4*)&Kc[row * QK_STR + c8 * 8] = v;
            }
            __syncthreads();
            const unsigned short* ka = &Kc[(wjj * 32 + l31) * QK_STR + lh * 8];
            const unsigned short* qa = &Qc[i_my * QK_STR + lh * 8];
#pragma unroll
            for (int ks = 0; ks < 8; ks++) {
                const int co = ks * 16;
                short8 fa = *(const short8*)(ka + co);
                short8 fb = *(const short8*)(qa + co);
                s = mfma_bf16(fa, fb, s);
            }
        }

        // ================= online softmax =================================
        float mx = -__builtin_inff();
#pragma unroll
        for (int r = 0; r < 16; r++) mx = fmaxf(mx, s[r]);
        mx = fmaxf(mx, __shfl_xor(mx, 32));                  // combine lh halves
        if (lh == 0) pmax[i_my * 8 + wjj] = mx;
        __syncthreads();                                     // sync1

        float4 pm0 = *(float4*)&pmax[i_my * 8];
        float4 pm1 = *(float4*)&pmax[i_my * 8 + 4];
        float m_new = fmaxf(m_st,
            fmaxf(fmaxf(fmaxf(pm0.x, pm0.y), fmaxf(pm0.z, pm0.w)),
                  fmaxf(fmaxf(pm1.x, pm1.y), fmaxf(pm1.z, pm1.w))));
        const float alpha = __expf(m_st - m_new);
        m_st = m_new;

        float sum = 0.f;
        {
            const int prow = i_my * P_STR + wjj * 32;
#pragma unroll
            for (int q = 0; q < 4; q++) {
                float p0 = __expf(s[4*q+0] - m_new), p1 = __expf(s[4*q+1] - m_new);
                float p2 = __expf(s[4*q+2] - m_new), p3 = __expf(s[4*q+3] - m_new);
                sum += (p0 + p1) + (p2 + p3);
                ushort4 h; h.x = f2bf(p0); h.y = f2bf(p1); h.z = f2bf(p2); h.w = f2bf(p3);
                *(ushort4*)&P[prow + 8 * q + 4 * lh] = h;
            }
        }
        sum += __shfl_xor(sum, 32);
        if (lh == 0) psum[i_my * 8 + wjj] = sum;
        if (lh == 0 && wjj == 0) alpha_s[i_my] = alpha;      // waves 0,1 cover i 0..63
        __syncthreads();                                     // sync2

        float4 ps0 = *(float4*)&psum[i_my * 8];
        float4 ps1 = *(float4*)&psum[i_my * 8 + 4];
        l_st = l_st * alpha + ((ps0.x + ps0.y) + (ps0.z + ps0.w))
                            + ((ps1.x + ps1.y) + (ps1.z + ps1.w));

        // rescale O (rows of PV mapping = wi*32 + 8q + 4lh + (0..3))
#pragma unroll
        for (int q = 0; q < 4; q++) {
            float4 a4 = *(float4*)&alpha_s[wi * 32 + 8 * q + 4 * lh];
            oA[4*q+0] *= a4.x; oA[4*q+1] *= a4.y; oA[4*q+2] *= a4.z; oA[4*q+3] *= a4.w;
            oB[4*q+0] *= a4.x; oB[4*q+1] *= a4.y; oB[4*q+2] *= a4.z; oB[4*q+3] *= a4.w;
        }

        // ================= O += P.V (j-chunks of 64) ======================
        for (int jc = 0; jc < 4; jc++) {
            __syncthreads();
#pragma unroll
            for (int p = 0; p < 4; p++) {                    // Vs: 512 d x 64 j
                int id = t + p * 1024;
                int d = id >> 3, c8 = id & 7;
                uint4 v = *(const uint4*)(vT + vbase + (size_t)d * NSEQ + kt + jc * 64 + c8 * 8);
                *(uint4*)&Vs[d * V_STR + c8 * 8] = v;
            }
            __syncthreads();
            const unsigned short* pa = &P[(wi * 32 + l31) * P_STR + jc * 64 + lh * 8];
            const unsigned short* va = &Vs[(wjj * 64 + l31) * V_STR + lh * 8];
            const unsigned short* vb = va + 32 * V_STR;
#pragma unroll
            for (int ksj = 0; ksj < 4; ksj++) {
                const int co = ksj * 16;
                short8 pfr = *(const short8*)(pa + co);
                oA = mfma_bf16(pfr, *(const short8*)(va + co), oA);
                oB = mfma_bf16(pfr, *(const short8*)(vb + co), oB);
            }
        }
    }

    // ================= epilogue: O / l ===================================
    if (lh == 0 && wjj == 0) l_s[i_my] = l_st;
    __syncthreads();
#pragma unroll
    for (int q = 0; q < 4; q++) {
        float4 l4 = *(float4*)&l_s[wi * 32 + 8 * q + 4 * lh];
        float iv0 = 1.f / l4.x, iv1 = 1.f / l4.y, iv2 = 1.f / l4.z, iv3 = 1.f / l4.w;
#pragma unroll
        for (int rr = 0; rr < 4; rr++) {
            const float ivr = (rr == 0) ? iv0 : (rr == 1) ? iv1 : (rr == 2) ? iv2 : iv3;
            const int i = wi * 32 + 8 * q + 4 * lh + rr;
            const size_t rowb = ((size_t)b * NSEQ + q0 + i) * D_DIM;
            out[rowb + wjj * 64 + l31]      = oA[4 * q + rr] * ivr;
            out[rowb + wjj * 64 + 32 + l31] = oB[4 * q + rr] * ivr;
        }
    }
}

extern "C" void kernel_launch(void* const* d_in, const int* in_sizes, int n_in,
                              void* d_out, int out_size, void* d_ws, size_t ws_size,
                              hipStream_t stream)
{
    (void)in_sizes; (void)n_in; (void)out_size; (void)ws_size;
    const float* x    = (const float*)d_in[0];
    const float* W    = (const float*)d_in[1];
    const float* bias = (const float*)d_in[2];
    float* out = (float*)d_out;

    unsigned short* qs = (unsigned short*)d_ws;              // [16384][512]
    unsigned short* kk = qs + (size_t)16384 * 512;           // [16384][512]
    unsigned short* vT = kk + (size_t)16384 * 512;           // [4][512][4096]

    qkv_gemm<<<dim3(128, 12), 256, 0, stream>>>(x, W, bias, qs, kk, vT);
    flash_attn<<<dim3(NSEQ / 64, BATCH), 1024, 0, stream>>>(qs, kk, vT, out);
}